// Round 2
// baseline (67956.799 us; speedup 1.0000x reference)
//
#include <hip/hip_runtime.h>
#include <cstdint>
#include <cstddef>

// Problem dims
#define TT   1024
#define BB   128
#define FEAT 138
#define FPAD 160          // F padded to multiple of 32 for K-tiling
#define HH   1024
#define G4   4096         // 4*H gate rows
#define VV   128
#define MM   128          // MLP hidden
#define MMP  136          // padded LDS row for mid[] (kills 16-way b128 bank conflict)
#define K1   (FPAD + HH)  // 1184
#define K2   (2 * HH)     // 2048
#define NBLK 512          // 256 LSTM1 + 256 LSTM2 blocks; 2 blocks/CU
#define GPAD 33           // gall row stride (pad 32->33: conflict-free epilogue stores)
#define GSZ  (16 * GPAD)  // floats per gate in gall

typedef __bf16 bf16x8 __attribute__((ext_vector_type(8)));
typedef float  f32x4  __attribute__((ext_vector_type(4)));
typedef unsigned short u16;

__device__ __forceinline__ u16 f2bf(float f) {  // RNE float->bf16
  uint32_t u = __float_as_uint(f);
  u += 0x7fffu + ((u >> 16) & 1u);
  return (u16)(u >> 16);
}
__device__ __forceinline__ float sigm(float x) { return 1.0f / (1.0f + __expf(-x)); }
__device__ __forceinline__ float tanh_(float x) {
  float e = __expf(-2.0f * fabsf(x));           // e in (0,1]: no inf/NaN
  float t = (1.0f - e) / (1.0f + e);
  return x < 0.0f ? -t : t;
}

// ---------------- prep kernels ----------------

__global__ void conv_w1cat(const float* __restrict__ Wih, const float* __restrict__ Whh,
                           const float* __restrict__ bi, const float* __restrict__ bh,
                           u16* __restrict__ dst, float* __restrict__ bsum) {
  int r = blockIdx.x;
  if (threadIdx.x == 0) bsum[r] = bi[r] + bh[r];
  for (int k = threadIdx.x; k < K1; k += 256) {
    float v;
    if (k < FPAD) v = (k < FEAT) ? Wih[(size_t)r * FEAT + k] : 0.0f;
    else          v = Whh[(size_t)r * HH + (k - FPAD)];
    dst[(size_t)r * K1 + k] = f2bf(v);
  }
}
__global__ void conv_w2cat(const float* __restrict__ Wih, const float* __restrict__ Whh,
                           const float* __restrict__ bi, const float* __restrict__ bh,
                           u16* __restrict__ dst, float* __restrict__ bsum) {
  int r = blockIdx.x;
  if (threadIdx.x == 0) bsum[r] = bi[r] + bh[r];
  for (int k = threadIdx.x; k < K2; k += 256) {
    float v = (k < HH) ? Wih[(size_t)r * HH + k] : Whh[(size_t)r * HH + (k - HH)];
    dst[(size_t)r * K2 + k] = f2bf(v);
  }
}
__global__ void conv_mlp(const float* __restrict__ W1, const float* __restrict__ W2,
                         u16* __restrict__ A, u16* __restrict__ Bm) {
  int i = blockIdx.x * 256 + threadIdx.x;          // 576*256 covers 131072 + 16384
  if (i < MM * HH) A[i] = f2bf(W1[i]);
  else {
    int j = i - MM * HH;
    if (j < VV * MM) Bm[j] = f2bf(W2[j]);
  }
}
__global__ void conv_x(const float* __restrict__ x, u16* __restrict__ Xb) {
  const int total = TT * BB * FPAD;
  int stride = gridDim.x * 256;
  for (int i = blockIdx.x * 256 + threadIdx.x; i < total; i += stride) {
    int tb = i / FPAD, k = i - tb * FPAD;
    Xb[i] = (k < FEAT) ? f2bf(x[(size_t)tb * FEAT + k]) : (u16)0;
  }
}
__global__ void zero_ws(uint4* __restrict__ p, int n16) {
  int i = blockIdx.x * 256 + threadIdx.x;
  if (i < n16) p[i] = uint4{0, 0, 0, 0};
}

// ---------------- persistent fused kernel ----------------

__device__ __forceinline__ void grid_barrier(unsigned* __restrict__ bar, int ph) {
  __syncthreads();
  if (threadIdx.x == 0) {
    const unsigned g = (unsigned)ph + 1u;
    // level 1: 8 group counters (64B apart), 64 blocks each; monotonic
    unsigned v = __hip_atomic_fetch_add(&bar[(blockIdx.x & 7) * 16], 1u,
                                        __ATOMIC_ACQ_REL, __HIP_MEMORY_SCOPE_AGENT);
    if (v == 64u * g - 1u) {
      unsigned w = __hip_atomic_fetch_add(&bar[128], 1u,
                                          __ATOMIC_ACQ_REL, __HIP_MEMORY_SCOPE_AGENT);
      if (w == 8u * g - 1u)
        __hip_atomic_store(&bar[144], g, __ATOMIC_RELEASE, __HIP_MEMORY_SCOPE_AGENT);
    }
    while (__hip_atomic_load(&bar[144], __ATOMIC_RELAXED, __HIP_MEMORY_SCOPE_AGENT) < g)
      __builtin_amdgcn_s_sleep(2);
    __builtin_amdgcn_fence(__ATOMIC_ACQUIRE, "agent");
  }
  __syncthreads();
}

// One LSTM slice: 16 h-cols x 32 batch, K = len0(seg0 from src0) + len1(seg1 from src1).
__device__ __forceinline__ void lstm_block_p(
    const u16* __restrict__ Wcat, int len0,
    const u16* __restrict__ src0, int ld0,
    const u16* __restrict__ src1, int ld1, int len1,
    float* __restrict__ creg,                 // [2] persistent cell state
    u16* __restrict__ hout,
    const float* __restrict__ bsum,
    int hc0, int bs, float* __restrict__ gall, int tid, int Ktot)
{
  const int wave = tid >> 6, lane = tid & 63;
  const int quad = lane >> 4, l16 = lane & 15;
  const int koff = quad * 8;
  const u16* arow = Wcat + (size_t)(wave * HH + hc0 + l16) * Ktot + koff;
  const u16* b0p = src0 + (size_t)(bs + l16) * ld0 + koff;
  const u16* b1p = src1 + (size_t)(bs + l16) * ld1 + koff;
  const size_t s0 = (size_t)16 * ld0, s1 = (size_t)16 * ld1;

  f32x4 acc0 = {0,0,0,0}, acc1 = {0,0,0,0};
#pragma unroll 8
  for (int kk = 0; kk < len0; kk += 32) {
    bf16x8 a  = *(const bf16x8*)(arow + kk);
    bf16x8 b0 = *(const bf16x8*)(b0p + kk);
    bf16x8 b1 = *(const bf16x8*)(b0p + s0 + kk);
    acc0 = __builtin_amdgcn_mfma_f32_16x16x32_bf16(a, b0, acc0, 0, 0, 0);
    acc1 = __builtin_amdgcn_mfma_f32_16x16x32_bf16(a, b1, acc1, 0, 0, 0);
  }
  const u16* arow1 = arow + len0;
#pragma unroll 8
  for (int kk = 0; kk < len1; kk += 32) {
    bf16x8 a  = *(const bf16x8*)(arow1 + kk);
    bf16x8 b0 = *(const bf16x8*)(b1p + kk);
    bf16x8 b1 = *(const bf16x8*)(b1p + s1 + kk);
    acc0 = __builtin_amdgcn_mfma_f32_16x16x32_bf16(a, b0, acc0, 0, 0, 0);
    acc1 = __builtin_amdgcn_mfma_f32_16x16x32_bf16(a, b1, acc1, 0, 0, 0);
  }

  // D layout: col = lane&15 (n), row = quad*4+reg (m). Exchange gates via LDS.
  float* gw = gall + wave * GSZ;
  const int mrow = quad * 4;
#pragma unroll
  for (int r = 0; r < 4; ++r) {
    gw[(mrow + r) * GPAD +      l16] = acc0[r];
    gw[(mrow + r) * GPAD + 16 + l16] = acc1[r];
  }
  __syncthreads();

  // Elementwise cell update: 16 m x 32 n; thread -> (n = tid&31, m = (tid>>5)*2 + d)
  const int n = tid & 31, mp = (tid >> 5) * 2;
  const int b = bs + n;
  u16 hv[2];
#pragma unroll
  for (int d = 0; d < 2; ++d) {
    int m = mp + d;
    int hc = hc0 + m;
    float gi = gall[0 * GSZ + m * GPAD + n] + bsum[hc];
    float gf = gall[1 * GSZ + m * GPAD + n] + bsum[HH + hc];
    float gg = gall[2 * GSZ + m * GPAD + n] + bsum[2 * HH + hc];
    float go = gall[3 * GSZ + m * GPAD + n] + bsum[3 * HH + hc];
    float iv = sigm(gi), fv = sigm(gf), gv = tanh_(gg), ov = sigm(go);
    float cv = fv * creg[d] + iv * gv;          // c stays fp32 in registers
    creg[d] = cv;
    hv[d] = f2bf(ov * tanh_(cv));
  }
  *(uint32_t*)(hout + (size_t)b * HH + hc0 + mp) =
      (uint32_t)hv[0] | ((uint32_t)hv[1] << 16);
}

__device__ __forceinline__ void mlp_block(
    const u16* __restrict__ WmA, const u16* __restrict__ WmB,
    const u16* __restrict__ h2src, const float* __restrict__ bm1,
    const float* __restrict__ bm2, float* __restrict__ out,
    int t2, int bs, u16* __restrict__ mid, int tid)
{
  const int wave = tid >> 6, lane = tid & 63, quad = lane >> 4, l16 = lane & 15;
  const int koff = quad * 8;
  const u16* brow = h2src + (size_t)(bs + l16) * HH + koff;
  const u16* a0r = WmA + (size_t)(wave * 32 + l16) * HH + koff;
  const u16* a1r = WmA + (size_t)(wave * 32 + 16 + l16) * HH + koff;
  f32x4 acc0 = {0,0,0,0}, acc1 = {0,0,0,0};
#pragma unroll 4
  for (int kk = 0; kk < HH; kk += 32) {
    bf16x8 b  = *(const bf16x8*)(brow + kk);
    bf16x8 x0 = *(const bf16x8*)(a0r + kk);
    bf16x8 x1 = *(const bf16x8*)(a1r + kk);
    acc0 = __builtin_amdgcn_mfma_f32_16x16x32_bf16(x0, b, acc0, 0, 0, 0);
    acc1 = __builtin_amdgcn_mfma_f32_16x16x32_bf16(x1, b, acc1, 0, 0, 0);
  }
  const float SC = 1.0507009873554804934193349852946f;
  const float AL = 1.6732632423543772848170429916717f;
#pragma unroll
  for (int mt = 0; mt < 2; ++mt) {
    f32x4 ac = mt ? acc1 : acc0;
#pragma unroll
    for (int r = 0; r < 4; ++r) {
      int m = wave * 32 + mt * 16 + quad * 4 + r;
      float v = ac[r] + bm1[m];
      v = v > 0.0f ? SC * v : SC * AL * (__expf(v) - 1.0f);    // SELU
      mid[l16 * MMP + m] = f2bf(v);
    }
  }
  __syncthreads();
  const u16* c0r = WmB + (size_t)(wave * 32 + l16) * MM + koff;
  const u16* c1r = WmB + (size_t)(wave * 32 + 16 + l16) * MM + koff;
  const u16* mrow = mid + l16 * MMP + koff;
  f32x4 o0 = {0,0,0,0}, o1 = {0,0,0,0};
#pragma unroll
  for (int kk = 0; kk < MM; kk += 32) {
    bf16x8 b  = *(const bf16x8*)(mrow + kk);
    bf16x8 x0 = *(const bf16x8*)(c0r + kk);
    bf16x8 x1 = *(const bf16x8*)(c1r + kk);
    o0 = __builtin_amdgcn_mfma_f32_16x16x32_bf16(x0, b, o0, 0, 0, 0);
    o1 = __builtin_amdgcn_mfma_f32_16x16x32_bf16(x1, b, o1, 0, 0, 0);
  }
  float* orow = out + ((size_t)t2 * BB + bs + l16) * VV;
#pragma unroll
  for (int mt = 0; mt < 2; ++mt) {
    f32x4 ac = mt ? o1 : o0;
    int vb = wave * 32 + mt * 16 + quad * 4;
    float4 o4;
    o4.x = ac[0] + bm2[vb];
    o4.y = ac[1] + bm2[vb + 1];
    o4.z = ac[2] + bm2[vb + 2];
    o4.w = ac[3] + bm2[vb + 3];
    *(float4*)(orow + vb) = o4;
  }
}

__global__ __launch_bounds__(256, 2) void fused_lstm(
    const u16* __restrict__ W1c, const u16* __restrict__ W2c,
    const u16* __restrict__ WmA, const u16* __restrict__ WmB,
    const u16* __restrict__ Xb, u16* __restrict__ h1b, u16* __restrict__ h2b,
    const float* __restrict__ bsum1, const float* __restrict__ bsum2,
    const float* __restrict__ bm1, const float* __restrict__ bm2,
    float* __restrict__ out, unsigned* __restrict__ bar)
{
  __shared__ float gall[4 * GSZ];       // 8448B; reused as u16 mid[16][MMP] by MLP
  const int bid = blockIdx.x, tid = threadIdx.x;
  const size_t HB = (size_t)BB * HH;
  float creg[2] = {0.0f, 0.0f};

  const bool isL1 = bid < 256;
  const int rid = isL1 ? bid : bid - 256;
  // slice mapping: bs-siblings are 8 apart -> same XCD shares the weight slice
  const int bs_ = ((rid >> 3) & 3) * 32;
  const int hc0 = 16 * (((rid >> 5) << 3) | (rid & 7));
  const bool doMLP = (bid < 8);

  for (int ph = 0; ph < TT + 2; ++ph) {
    if (isL1) {
      if (ph < TT) {
        lstm_block_p(W1c, FPAD, Xb + (size_t)ph * BB * FPAD, FPAD,
                     h1b + (size_t)((ph - 1) & 1) * HB, HH, HH,
                     creg, h1b + (size_t)(ph & 1) * HB,
                     bsum1, hc0, bs_, gall, tid, K1);
      }
      if (doMLP && ph >= 2) {
        __syncthreads();   // protect gall before reuse as mid[]
        mlp_block(WmA, WmB, h2b + (size_t)(ph & 1) * HB, bm1, bm2, out,
                  ph - 2, bid * 16, (u16*)gall, tid);
      }
    } else {
      if (ph >= 1 && ph <= TT) {
        lstm_block_p(W2c, HH, h1b + (size_t)((ph - 1) & 1) * HB, HH,
                     h2b + (size_t)(ph & 1) * HB, HH, HH,
                     creg, h2b + (size_t)((ph - 1) & 1) * HB,
                     bsum2, hc0, bs_, gall, tid, K2);
      }
    }
    grid_barrier(bar, ph);
  }
}

extern "C" void kernel_launch(void* const* d_in, const int* in_sizes, int n_in,
                              void* d_out, int out_size, void* d_ws, size_t ws_size,
                              hipStream_t stream)
{
  const float* x    = (const float*)d_in[0];
  const float* Wih1 = (const float*)d_in[1];
  const float* bih1 = (const float*)d_in[2];
  const float* Whh1 = (const float*)d_in[3];
  const float* bhh1 = (const float*)d_in[4];
  const float* Wih2 = (const float*)d_in[5];
  const float* bih2 = (const float*)d_in[6];
  const float* Whh2 = (const float*)d_in[7];
  const float* bhh2 = (const float*)d_in[8];
  const float* W1   = (const float*)d_in[9];
  const float* b1   = (const float*)d_in[10];
  const float* W2   = (const float*)d_in[11];
  const float* b2   = (const float*)d_in[12];
  float* out = (float*)d_out;
  (void)in_sizes; (void)n_in; (void)out_size;

  char* ws = (char*)d_ws;
  size_t off = 0;
  auto alloc = [&](size_t n) { char* p = ws + off; off += (n + 255) & ~(size_t)255; return p; };
  u16* W1c   = (u16*)alloc((size_t)G4 * K1 * 2);        // 9.70 MB
  u16* W2c   = (u16*)alloc((size_t)G4 * K2 * 2);        // 16.78 MB
  u16* WmAp  = (u16*)alloc((size_t)MM * HH * 2);
  u16* WmBp  = (u16*)alloc((size_t)VV * MM * 2);
  u16* Xb    = (u16*)alloc((size_t)TT * BB * FPAD * 2); // 41.94 MB
  float* bs1 = (float*)alloc((size_t)G4 * 4);
  float* bs2 = (float*)alloc((size_t)G4 * 4);
  // zeroed region: h1b, h2b, bar contiguous
  u16* h1b   = (u16*)alloc(2 * (size_t)BB * HH * 2);    // 512 KB
  u16* h2b   = (u16*)alloc(2 * (size_t)BB * HH * 2);    // 512 KB
  unsigned* bar = (unsigned*)alloc(4096);
  if (ws_size < off) return;  // ~70 MB required

  conv_w1cat<<<G4, 256, 0, stream>>>(Wih1, Whh1, bih1, bhh1, W1c, bs1);
  conv_w2cat<<<G4, 256, 0, stream>>>(Wih2, Whh2, bih2, bhh2, W2c, bs2);
  conv_mlp<<<576, 256, 0, stream>>>(W1, W2, WmAp, WmBp);
  conv_x<<<8192, 256, 0, stream>>>(x, Xb);
  {
    int n16 = (int)((2 * (size_t)BB * HH * 2 * 2 + 4096) / 16);  // h1b+h2b+bar
    zero_ws<<<(n16 + 255) / 256, 256, 0, stream>>>((uint4*)h1b, n16);
  }

  void* args[] = { (void*)&W1c, (void*)&W2c, (void*)&WmAp, (void*)&WmBp,
                   (void*)&Xb, (void*)&h1b, (void*)&h2b, (void*)&bs1, (void*)&bs2,
                   (void*)&b1, (void*)&b2, (void*)&out, (void*)&bar };
  hipError_t err = hipLaunchCooperativeKernel((const void*)fused_lstm,
                                              dim3(NBLK), dim3(256), args, 0, stream);
  if (err != hipSuccess) {
    // fallback: plain launch (grid 512 @ 2 blocks/CU is co-resident on 256 CUs)
    fused_lstm<<<dim3(NBLK), dim3(256), 0, stream>>>(W1c, W2c, WmAp, WmBp, Xb,
                                                     h1b, h2b, bs1, bs2, b1, b2,
                                                     out, bar);
  }
}

// Round 3
// 20062.024 us; speedup vs baseline: 3.3873x; 3.3873x over previous
//
#include <hip/hip_runtime.h>
#include <cstdint>
#include <cstddef>

// Problem dims
#define TT   1024
#define BB   128
#define FEAT 138
#define FPAD 160            // x K-pad (20 chunks of 8)
#define HH   1024
#define VV   128
#define MM   128
#define K1   (FPAD + HH)    // 1184 = 148 chunks
#define K2   (2 * HH)       // 2048 = 256 chunks
#define HCH  1024           // u16 per k-chunk of h-like buffers: 128 b x 8 k
#define H1N  131072         // u16 per h buffer (128 chunks)
#define MIDN 16384          // u16 per mid buffer (16 chunks)
// LDS padded row strides (elements); all give row-stride % 32 banks = 4 -> 2-way max
#define PK1  1192
#define PK2  2056
#define PKM1 1032
#define PKM2 136
// LDS layout (bytes)
#define OFF_WM  76288       // after L1 A-slice (32*1192*2); L2 A-slice is 131584
#define OFF_STG 131584
#define LDSZ    (131584 + 8 * 1024)   // 139,776 B -> 1 block/CU

typedef __bf16 bf16x8 __attribute__((ext_vector_type(8)));
typedef float  f32x4  __attribute__((ext_vector_type(4)));
typedef unsigned short u16;

__device__ __forceinline__ u16 f2bf(float f) {  // RNE float->bf16
  uint32_t u = __float_as_uint(f);
  u += 0x7fffu + ((u >> 16) & 1u);
  return (u16)(u >> 16);
}
__device__ __forceinline__ float sigm(float x) { return 1.0f / (1.0f + __expf(-x)); }
__device__ __forceinline__ float tanh_(float x) {
  float e = __expf(-2.0f * fabsf(x));
  float t = (1.0f - e) / (1.0f + e);
  return x < 0.0f ? -t : t;
}

// ---------------- prep kernels ----------------
// Weight layouts: gate-interleaved rows r' = hc*4 + gate, K-major concat.
__global__ void conv_w1i(const float* __restrict__ Wih, const float* __restrict__ Whh,
                         const float* __restrict__ bi, const float* __restrict__ bh,
                         u16* __restrict__ dst, float* __restrict__ bsum) {
  int rp = blockIdx.x;                 // 4096
  int hc = rp >> 2, g = rp & 3;
  int sr = g * HH + hc;
  if (threadIdx.x == 0) bsum[rp] = bi[sr] + bh[sr];
  for (int k = threadIdx.x; k < K1; k += 256) {
    float v;
    if (k < FPAD) v = (k < FEAT) ? Wih[(size_t)sr * FEAT + k] : 0.0f;
    else          v = Whh[(size_t)sr * HH + (k - FPAD)];
    dst[(size_t)rp * K1 + k] = f2bf(v);
  }
}
__global__ void conv_w2i(const float* __restrict__ Wih, const float* __restrict__ Whh,
                         const float* __restrict__ bi, const float* __restrict__ bh,
                         u16* __restrict__ dst, float* __restrict__ bsum) {
  int rp = blockIdx.x;
  int hc = rp >> 2, g = rp & 3;
  int sr = g * HH + hc;
  if (threadIdx.x == 0) bsum[rp] = bi[sr] + bh[sr];
  for (int k = threadIdx.x; k < K2; k += 256) {
    float v = (k < HH) ? Wih[(size_t)sr * HH + k] : Whh[(size_t)sr * HH + (k - HH)];
    dst[(size_t)rp * K2 + k] = f2bf(v);
  }
}
__global__ void conv_mlpw(const float* __restrict__ W1, const float* __restrict__ W2,
                          u16* __restrict__ A, u16* __restrict__ Bm) {
  int i = blockIdx.x * 256 + threadIdx.x;          // 576*256 covers 131072+16384
  if (i < MM * HH) A[i] = f2bf(W1[i]);
  else {
    int j = i - MM * HH;
    if (j < VV * MM) Bm[j] = f2bf(W2[j]);
  }
}
// x -> chunked bf16 [t][20 c][128 b][8 k]
__global__ void conv_x(const float* __restrict__ x, u16* __restrict__ Xb) {
  int blk = blockIdx.x;                 // TT*20
  int t = blk / 20, c = blk % 20;
  int b = threadIdx.x;                  // 128
  if (b >= BB) return;
  const float* src = x + ((size_t)t * BB + b) * FEAT;
  u16 v[8];
#pragma unroll
  for (int e = 0; e < 8; ++e) {
    int col = c * 8 + e;
    v[e] = (col < FEAT) ? f2bf(src[col]) : (u16)0;
  }
  *(uint4*)(Xb + (((size_t)t * 20 + c) * BB + b) * 8) = *(uint4*)v;
}
__global__ void zero_ws(uint4* __restrict__ p, int n16) {
  int i = blockIdx.x * 256 + threadIdx.x;
  if (i < n16) p[i] = uint4{0, 0, 0, 0};
}

// ---------------- fused persistent kernel ----------------

// K-segment accumulate: B streamed from global (chunked layout), A from LDS.
__device__ __forceinline__ void seg_acc(const u16* __restrict__ bp,
                                        const u16* __restrict__ a0,
                                        const u16* __restrict__ a1,
                                        int kbase, int steps,
                                        f32x4& acc0, f32x4& acc1)
{
#pragma unroll 4
  for (int s = 0; s < steps; ++s) {
    bf16x8 bf  = *(const bf16x8*)(bp + (size_t)s * 4096);   // 4 chunks/step
    bf16x8 af0 = *(const bf16x8*)(a0 + kbase + s * 32);
    bf16x8 af1 = *(const bf16x8*)(a1 + kbase + s * 32);
    acc0 = __builtin_amdgcn_mfma_f32_16x16x32_bf16(af0, bf, acc0, 0, 0, 0);
    acc1 = __builtin_amdgcn_mfma_f32_16x16x32_bf16(af1, bf, acc1, 0, 0, 0);
  }
}

__device__ __forceinline__ void lstm_epi(const f32x4& acc, const f32x4& bv,
                                         float& c, u16& hv) {
  float gi = acc[0] + bv[0], gf = acc[1] + bv[1];
  float gg = acc[2] + bv[2], go = acc[3] + bv[3];
  float iv = sigm(gi), fv = sigm(gf), gv = tanh_(gg), ov = sigm(go);
  c = fv * c + iv * gv;                 // fp32 cell state in registers
  hv = f2bf(ov * tanh_(c));
}

// Grid barrier: relaxed hierarchical counters, ONE release fence + ONE acquire
// fence per block per phase (r2's per-atomic ACQ_REL caused ~64 L2 wbinv per
// XCD per phase -> 63us phases).
__device__ __forceinline__ void gbar(unsigned* __restrict__ bar, unsigned g) {
  __syncthreads();                      // drains vmcnt before s_barrier
  if (threadIdx.x == 0) {
    __builtin_amdgcn_fence(__ATOMIC_RELEASE, "agent");
    unsigned v = __hip_atomic_fetch_add(&bar[(blockIdx.x & 7) * 16], 1u,
                                        __ATOMIC_RELAXED, __HIP_MEMORY_SCOPE_AGENT);
    if (v == 32u * g - 1u) {
      unsigned w = __hip_atomic_fetch_add(&bar[128], 1u,
                                          __ATOMIC_RELAXED, __HIP_MEMORY_SCOPE_AGENT);
      if (w == 8u * g - 1u)
        __hip_atomic_store(&bar[144], g, __ATOMIC_RELAXED, __HIP_MEMORY_SCOPE_AGENT);
    }
    while (__hip_atomic_load(&bar[144], __ATOMIC_RELAXED,
                             __HIP_MEMORY_SCOPE_AGENT) < g)
      __builtin_amdgcn_s_sleep(8);
    __builtin_amdgcn_fence(__ATOMIC_ACQUIRE, "agent");
  }
  __syncthreads();
}

__global__ __launch_bounds__(512, 1) void fused_lstm(
    const u16* __restrict__ W1i, const u16* __restrict__ W2i,
    const u16* __restrict__ W1m, const u16* __restrict__ W2m,
    const u16* __restrict__ Xb, u16* __restrict__ h1b, u16* __restrict__ h2b,
    u16* __restrict__ midb,
    const float* __restrict__ bs1, const float* __restrict__ bs2,
    const float* __restrict__ bm1, const float* __restrict__ bm2,
    float* __restrict__ out, unsigned* __restrict__ bar)
{
  extern __shared__ char smem[];
  const int tid = threadIdx.x, bid = blockIdx.x;
  const int wv = tid >> 6, lane = tid & 63, q = lane >> 4, l16 = lane & 15;
  const bool isL1 = bid < 128;
  const int j = isL1 ? bid : bid - 128;          // hc-slice: hc = j*8 .. j*8+8
  u16* Alds = (u16*)smem;
  u16* Wm   = (u16*)(smem + OFF_WM);
  char* stg = smem + OFF_STG + wv * 1024;

  // ---- one-time LDS weight fill ----
  if (isL1) {
    for (int i = tid; i < 32 * 148; i += 512) {  // 32 rows x 1184 (pad 1192)
      int r = i / 148, c8 = i % 148;
      *(uint4*)(Alds + r * PK1 + c8 * 8) =
          *(const uint4*)(W1i + ((size_t)(j * 32 + r)) * K1 + c8 * 8);
    }
    if (j < 64) {
      int m0 = (j & 7) * 16;
      for (int i = tid; i < 16 * 128; i += 512) {
        int r = i >> 7, c8 = i & 127;
        *(uint4*)(Wm + r * PKM1 + c8 * 8) =
            *(const uint4*)(W1m + ((size_t)(m0 + r)) * HH + c8 * 8);
      }
    } else {
      int v0 = ((j - 64) & 7) * 16;
      for (int i = tid; i < 16 * 16; i += 512) {
        int r = i >> 4, c8 = i & 15;
        *(uint4*)(Wm + r * PKM2 + c8 * 8) =
            *(const uint4*)(W2m + ((size_t)(v0 + r)) * MM + c8 * 8);
      }
    }
  } else {
    for (int i = tid; i < 32 * 256; i += 512) {  // 32 rows x 2048 (pad 2056)
      int r = i >> 8, c8 = i & 255;
      *(uint4*)(Alds + r * PK2 + c8 * 8) =
          *(const uint4*)(W2i + ((size_t)(j * 32 + r)) * K2 + c8 * 8);
    }
  }
  // per-lane persistent biases: acc reg r = gate r of hc = j*8 + q (tile0), +4 (tile1)
  f32x4 bv0, bv1;
  {
    const float* bs = isL1 ? bs1 : bs2;
    bv0 = *(const f32x4*)(bs + (j * 8 + q) * 4);
    bv1 = *(const f32x4*)(bs + (j * 8 + 4 + q) * 4);
  }
  f32x4 bmv = {0, 0, 0, 0};
  if (isL1) {
    if (j < 64) bmv = *(const f32x4*)(bm1 + (j & 7) * 16 + q * 4);
    else        bmv = *(const f32x4*)(bm2 + ((j - 64) & 7) * 16 + q * 4);
  }
  __syncthreads();

  float c0 = 0.0f, c1v = 0.0f;          // persistent cell state (2 hc per lane)
  const int nb = wv * 16;               // batch tile of this wave

  for (int p = 0; p < TT + 3; ++p) {
    if (isL1) {
      if (p < TT) {                     // ---- LSTM1, t = p ----
        const u16* xl  = Xb + (((size_t)p * 20 + q) * BB + nb + l16) * 8;
        const u16* h1p = h1b + (size_t)((p - 1) & 1) * H1N + q * HCH + (nb + l16) * 8;
        const u16* a0 = Alds + l16 * PK1 + q * 8;
        const u16* a1 = Alds + (16 + l16) * PK1 + q * 8;
        f32x4 acc0 = {0, 0, 0, 0}, acc1 = {0, 0, 0, 0};
        seg_acc(xl,  a0, a1, 0,   5,  acc0, acc1);   // k 0..160
        seg_acc(h1p, a0, a1, 160, 32, acc0, acc1);   // k 160..1184
        u16 hv0, hv1;
        lstm_epi(acc0, bv0, c0, hv0);
        lstm_epi(acc1, bv1, c1v, hv1);
        u16* st = (u16*)stg;            // [16 b][8 hc]
        st[l16 * 8 + q] = hv0;
        st[l16 * 8 + 4 + q] = hv1;
        if (lane < 16) {
          uint4 vq = *(uint4*)(st + lane * 8);
          *(uint4*)(h1b + (size_t)(p & 1) * H1N + (size_t)j * HCH + (nb + lane) * 8) = vq;
        }
      }
      if (wv == 0 && j < 64 && p >= 2 && p <= TT + 1) {   // ---- MLP mid, t = p-2 ----
        int jm = j & 7, jb = j >> 3;
        const u16* bsrc = h2b + (size_t)(p & 1) * H1N + q * HCH + (jb * 16 + l16) * 8;
        const u16* am = Wm + l16 * PKM1 + q * 8;
        f32x4 acc = {0, 0, 0, 0};
#pragma unroll 4
        for (int s = 0; s < 32; ++s) {
          bf16x8 bf = *(const bf16x8*)(bsrc + (size_t)s * 4096);
          bf16x8 af = *(const bf16x8*)(am + s * 32);
          acc = __builtin_amdgcn_mfma_f32_16x16x32_bf16(af, bf, acc, 0, 0, 0);
        }
        const float SC = 1.0507009873554804934193349852946f;
        const float AL = 1.6732632423543772848170429916717f;
        u16* st16 = (u16*)stg;          // [16 b][16 mid]
#pragma unroll
        for (int r = 0; r < 4; ++r) {
          float v = acc[r] + bmv[r];
          v = v > 0.0f ? SC * v : SC * AL * (__expf(v) - 1.0f);
          st16[l16 * 16 + q * 4 + r] = f2bf(v);
        }
        if (lane < 16) {
          uint4 v0 = *(uint4*)(st16 + lane * 16);
          uint4 v1 = *(uint4*)(st16 + lane * 16 + 8);
          u16* mc = midb + (size_t)(p & 1) * MIDN;       // buf (p-2)&1 == p&1
          *(uint4*)(mc + (size_t)(2 * jm) * HCH + (jb * 16 + lane) * 8) = v0;
          *(uint4*)(mc + (size_t)(2 * jm + 1) * HCH + (jb * 16 + lane) * 8) = v1;
        }
      }
      if (wv == 0 && j >= 64 && p >= 3) {                 // ---- MLP out, t = p-3 ----
        int jj = j - 64, jv = jj & 7, jb = jj >> 3;
        const u16* bsrc = midb + (size_t)((p - 3) & 1) * MIDN + q * HCH +
                          (jb * 16 + l16) * 8;
        const u16* am = Wm + l16 * PKM2 + q * 8;
        f32x4 acc = {0, 0, 0, 0};
#pragma unroll
        for (int s = 0; s < 4; ++s) {
          bf16x8 bf = *(const bf16x8*)(bsrc + (size_t)s * 4096);
          bf16x8 af = *(const bf16x8*)(am + s * 32);
          acc = __builtin_amdgcn_mfma_f32_16x16x32_bf16(af, bf, acc, 0, 0, 0);
        }
        float* stf = (float*)stg;       // [16 b][16 v] fp32
#pragma unroll
        for (int r = 0; r < 4; ++r) stf[l16 * 16 + q * 4 + r] = acc[r] + bmv[r];
        if (lane < 16) {
          float* orow = out + ((size_t)(p - 3) * BB + jb * 16 + lane) * VV + jv * 16;
          uint4* s4 = (uint4*)(stf + lane * 16);
          *(uint4*)(orow + 0)  = s4[0];
          *(uint4*)(orow + 4)  = s4[1];
          *(uint4*)(orow + 8)  = s4[2];
          *(uint4*)(orow + 12) = s4[3];
        }
      }
    } else {
      if (p >= 1 && p <= TT) {          // ---- LSTM2, t = p-1 ----
        int t = p - 1;
        const u16* h1c = h1b + (size_t)(t & 1) * H1N + q * HCH + (nb + l16) * 8;
        const u16* h2p = h2b + (size_t)((t - 1) & 1) * H1N + q * HCH + (nb + l16) * 8;
        const u16* a0 = Alds + l16 * PK2 + q * 8;
        const u16* a1 = Alds + (16 + l16) * PK2 + q * 8;
        f32x4 acc0 = {0, 0, 0, 0}, acc1 = {0, 0, 0, 0};
        seg_acc(h1c, a0, a1, 0,    32, acc0, acc1);  // k 0..1024   (W_ih2 · h1)
        seg_acc(h2p, a0, a1, 1024, 32, acc0, acc1);  // k 1024..2048 (W_hh2 · h2)
        u16 hv0, hv1;
        lstm_epi(acc0, bv0, c0, hv0);
        lstm_epi(acc1, bv1, c1v, hv1);
        u16* st = (u16*)stg;
        st[l16 * 8 + q] = hv0;
        st[l16 * 8 + 4 + q] = hv1;
        if (lane < 16) {
          uint4 vq = *(uint4*)(st + lane * 8);
          *(uint4*)(h2b + (size_t)(t & 1) * H1N + (size_t)j * HCH + (nb + lane) * 8) = vq;
        }
      }
    }
    gbar(bar, (unsigned)p + 1u);
  }
}

extern "C" void kernel_launch(void* const* d_in, const int* in_sizes, int n_in,
                              void* d_out, int out_size, void* d_ws, size_t ws_size,
                              hipStream_t stream)
{
  const float* x    = (const float*)d_in[0];
  const float* Wih1 = (const float*)d_in[1];
  const float* bih1 = (const float*)d_in[2];
  const float* Whh1 = (const float*)d_in[3];
  const float* bhh1 = (const float*)d_in[4];
  const float* Wih2 = (const float*)d_in[5];
  const float* bih2 = (const float*)d_in[6];
  const float* Whh2 = (const float*)d_in[7];
  const float* bhh2 = (const float*)d_in[8];
  const float* W1   = (const float*)d_in[9];
  const float* b1   = (const float*)d_in[10];
  const float* W2   = (const float*)d_in[11];
  const float* b2   = (const float*)d_in[12];
  float* out = (float*)d_out;
  (void)in_sizes; (void)n_in; (void)out_size;

  char* ws = (char*)d_ws;
  size_t off = 0;
  auto alloc = [&](size_t n) { char* p = ws + off; off += (n + 255) & ~(size_t)255; return p; };
  u16* W1i   = (u16*)alloc((size_t)4096 * K1 * 2);      // 9.70 MB
  u16* W2i   = (u16*)alloc((size_t)4096 * K2 * 2);      // 16.78 MB
  u16* W1m   = (u16*)alloc((size_t)MM * HH * 2);
  u16* W2m   = (u16*)alloc((size_t)VV * MM * 2);
  u16* Xb    = (u16*)alloc((size_t)TT * 20 * BB * 8 * 2);  // 41.94 MB
  float* bs1 = (float*)alloc(4096 * 4);
  float* bs2 = (float*)alloc(4096 * 4);
  // zeroed region (contiguous): h1b, h2b, bar
  u16* h1b   = (u16*)alloc(2 * (size_t)H1N * 2);        // 512 KB
  u16* h2b   = (u16*)alloc(2 * (size_t)H1N * 2);        // 512 KB
  unsigned* bar = (unsigned*)alloc(4096);
  u16* midb  = (u16*)alloc(2 * (size_t)MIDN * 2);       // 64 KB
  if (ws_size < off) return;  // ~70 MB required

  conv_w1i<<<4096, 256, 0, stream>>>(Wih1, Whh1, bih1, bhh1, W1i, bs1);
  conv_w2i<<<4096, 256, 0, stream>>>(Wih2, Whh2, bih2, bhh2, W2i, bs2);
  conv_mlpw<<<576, 256, 0, stream>>>(W1, W2, W1m, W2m);
  conv_x<<<TT * 20, 128, 0, stream>>>(x, Xb);
  {
    int n16 = (int)((2 * (size_t)H1N * 2 * 2 + 4096) / 16);   // h1b+h2b+bar
    zero_ws<<<(n16 + 255) / 256, 256, 0, stream>>>((uint4*)h1b, n16);
  }

  (void)hipFuncSetAttribute((const void*)fused_lstm,
                            hipFuncAttributeMaxDynamicSharedMemorySize, LDSZ);
  void* args[] = { (void*)&W1i, (void*)&W2i, (void*)&W1m, (void*)&W2m,
                   (void*)&Xb, (void*)&h1b, (void*)&h2b, (void*)&midb,
                   (void*)&bs1, (void*)&bs2, (void*)&b1, (void*)&b2,
                   (void*)&out, (void*)&bar };
  hipError_t err = hipLaunchCooperativeKernel((const void*)fused_lstm,
                                              dim3(256), dim3(512), args, LDSZ, stream);
  if (err != hipSuccess) {
    // 256 blocks x 1 block/CU on 256 CUs -> co-resident even without coop launch
    fused_lstm<<<dim3(256), dim3(512), LDSZ, stream>>>(W1i, W2i, W1m, W2m, Xb,
                                                       h1b, h2b, midb, bs1, bs2,
                                                       b1, b2, out, bar);
  }
}

// Round 4
// 19424.666 us; speedup vs baseline: 3.4985x; 1.0328x over previous
//
#include <hip/hip_runtime.h>
#include <cstdint>
#include <cstddef>

// Problem dims
#define TT   1024
#define BB   128
#define FEAT 138
#define FPAD 160            // x K-pad (20 chunks of 8)
#define HH   1024
#define VV   128
#define MM   128
#define K1   1184           // FPAD + HH
#define K1P  1280           // padded to 40 k-tiles of 32 (tiles 37..39 zero-A)
#define K2   2048           // 64 k-tiles
#define HCH  1024           // u16 per k-chunk of h-like buffers: 128 b x 8 k
#define H1N  131072         // u16 per h buffer (128 chunks)
#define MIDN 16384          // u16 per mid buffer (16 chunks)
#define PKM1 1032           // LDS row stride, MLP W1 slice
#define PKM2 136            // LDS row stride, MLP W2 slice
// LDS layout (bytes)
#define OFF_RED 0           // 32 KB: split-k reduction staging (4 regions x 8 KB)
#define OFF_WM  32768       // 33 KB: MLP weight slice
#define OFF_H   65792       // 2 KB: h epilogue transpose staging (2 x 1 KB)
#define OFF_M   67840       // 1 KB: MLP epilogue staging
#define LDSZ    68864

typedef __bf16 bf16x8 __attribute__((ext_vector_type(8)));
typedef float  f32x4  __attribute__((ext_vector_type(4)));
typedef unsigned short u16;

__device__ __forceinline__ u16 f2bf(float f) {  // RNE float->bf16
  uint32_t u = __float_as_uint(f);
  u += 0x7fffu + ((u >> 16) & 1u);
  return (u16)(u >> 16);
}
__device__ __forceinline__ float sigm(float x) { return 1.0f / (1.0f + __expf(-x)); }
__device__ __forceinline__ float tanh_(float x) {
  float e = __expf(-2.0f * fabsf(x));
  float t = (1.0f - e) / (1.0f + e);
  return x < 0.0f ? -t : t;
}

// ---------------- prep kernels ----------------
// Gate-interleaved rows r' = hc*4 + gate, K-major; W1 padded to K1P with zeros.
__global__ void conv_w1i(const float* __restrict__ Wih, const float* __restrict__ Whh,
                         const float* __restrict__ bi, const float* __restrict__ bh,
                         u16* __restrict__ dst, float* __restrict__ bsum) {
  int rp = blockIdx.x;                 // 4096
  int hc = rp >> 2, g = rp & 3;
  int sr = g * HH + hc;
  if (threadIdx.x == 0) bsum[rp] = bi[sr] + bh[sr];
  for (int k = threadIdx.x; k < K1P; k += 256) {
    float v = 0.0f;
    if (k < FPAD)    v = (k < FEAT) ? Wih[(size_t)sr * FEAT + k] : 0.0f;
    else if (k < K1) v = Whh[(size_t)sr * HH + (k - FPAD)];
    dst[(size_t)rp * K1P + k] = f2bf(v);
  }
}
__global__ void conv_w2i(const float* __restrict__ Wih, const float* __restrict__ Whh,
                         const float* __restrict__ bi, const float* __restrict__ bh,
                         u16* __restrict__ dst, float* __restrict__ bsum) {
  int rp = blockIdx.x;
  int hc = rp >> 2, g = rp & 3;
  int sr = g * HH + hc;
  if (threadIdx.x == 0) bsum[rp] = bi[sr] + bh[sr];
  for (int k = threadIdx.x; k < K2; k += 256) {
    float v = (k < HH) ? Wih[(size_t)sr * HH + k] : Whh[(size_t)sr * HH + (k - HH)];
    dst[(size_t)rp * K2 + k] = f2bf(v);
  }
}
__global__ void conv_mlpw(const float* __restrict__ W1, const float* __restrict__ W2,
                          u16* __restrict__ A, u16* __restrict__ Bm) {
  int i = blockIdx.x * 256 + threadIdx.x;          // 576*256 covers 131072+16384
  if (i < MM * HH) A[i] = f2bf(W1[i]);
  else {
    int j = i - MM * HH;
    if (j < VV * MM) Bm[j] = f2bf(W2[j]);
  }
}
// x -> chunked bf16 [t][20 c][128 b][8 k]
__global__ void conv_x(const float* __restrict__ x, u16* __restrict__ Xb) {
  int blk = blockIdx.x;                 // TT*20
  int t = blk / 20, c = blk % 20;
  int b = threadIdx.x;
  if (b >= BB) return;
  const float* src = x + ((size_t)t * BB + b) * FEAT;
  u16 v[8];
#pragma unroll
  for (int e = 0; e < 8; ++e) {
    int col = c * 8 + e;
    v[e] = (col < FEAT) ? f2bf(src[col]) : (u16)0;
  }
  *(uint4*)(Xb + (((size_t)t * 20 + c) * BB + b) * 8) = *(uint4*)v;
}
__global__ void zero_ws(uint4* __restrict__ p, int n16) {
  int i = blockIdx.x * 256 + threadIdx.x;
  if (i < n16) p[i] = uint4{0, 0, 0, 0};
}

// ---------------- fused persistent kernel helpers ----------------

__device__ __forceinline__ void mac_step(const bf16x8& a0, const bf16x8& a1,
                                         const u16* __restrict__ bptr,
                                         f32x4 (&acc)[2][4]) {
  bf16x8 Bf[4];
#pragma unroll
  for (int n = 0; n < 4; ++n) Bf[n] = *(const bf16x8*)(bptr + n * 128);
#pragma unroll
  for (int n = 0; n < 4; ++n) {
    acc[0][n] = __builtin_amdgcn_mfma_f32_16x16x32_bf16(a0, Bf[n], acc[0][n], 0, 0, 0);
    acc[1][n] = __builtin_amdgcn_mfma_f32_16x16x32_bf16(a1, Bf[n], acc[1][n], 0, 0, 0);
  }
}

__device__ __forceinline__ void red_write(float* __restrict__ rg,
                                          const f32x4 (&acc)[2][4], int lane) {
#pragma unroll
  for (int mt = 0; mt < 2; ++mt)
#pragma unroll
    for (int n = 0; n < 4; ++n)
      *(f32x4*)(rg + (mt * 4 + n) * 256 + lane * 4) = acc[mt][n];
}
__device__ __forceinline__ void red_add(const float* __restrict__ rg,
                                        f32x4 (&acc)[2][4], int lane) {
#pragma unroll
  for (int mt = 0; mt < 2; ++mt)
#pragma unroll
    for (int n = 0; n < 4; ++n)
      acc[mt][n] += *(const f32x4*)(rg + (mt * 4 + n) * 256 + lane * 4);
}

// kw0 epilogue: gates -> c,h (registers), LDS transpose, coalesced h chunk write.
__device__ __forceinline__ void lstm_tail(f32x4 (&acc)[2][4], const f32x4& bsv0,
                                          const f32x4& bsv1, float (&cst)[2][4],
                                          char* smem, int bh, int lane, int q, int l16,
                                          u16* __restrict__ houtChunk) {
  u16* st = (u16*)(smem + OFF_H) + bh * 512;
#pragma unroll
  for (int mt = 0; mt < 2; ++mt) {
    const f32x4 bsv = mt ? bsv1 : bsv0;
#pragma unroll
    for (int n = 0; n < 4; ++n) {
      float iv = sigm(acc[mt][n][0] + bsv[0]);
      float fv = sigm(acc[mt][n][1] + bsv[1]);
      float gv = tanh_(acc[mt][n][2] + bsv[2]);
      float ov = sigm(acc[mt][n][3] + bsv[3]);
      float c = fv * cst[mt][n] + iv * gv;
      cst[mt][n] = c;
      st[(n * 16 + l16) * 8 + mt * 4 + q] = f2bf(ov * tanh_(c));
    }
  }
  uint4 hv4 = *(uint4*)((u16*)(smem + OFF_H) + bh * 512 + lane * 8);
  *(uint4*)(houtChunk + ((size_t)bh * 64 + lane) * 8) = hv4;
}

// Grid barrier: one release + one acquire fence per block per phase.
__device__ __forceinline__ void gbar(unsigned* __restrict__ bar, unsigned g) {
  __syncthreads();
  if (threadIdx.x == 0) {
    __builtin_amdgcn_fence(__ATOMIC_RELEASE, "agent");
    unsigned v = __hip_atomic_fetch_add(&bar[(blockIdx.x & 7) * 16], 1u,
                                        __ATOMIC_RELAXED, __HIP_MEMORY_SCOPE_AGENT);
    if (v == 32u * g - 1u) {
      unsigned w = __hip_atomic_fetch_add(&bar[128], 1u,
                                          __ATOMIC_RELAXED, __HIP_MEMORY_SCOPE_AGENT);
      if (w == 8u * g - 1u)
        __hip_atomic_store(&bar[144], g, __ATOMIC_RELAXED, __HIP_MEMORY_SCOPE_AGENT);
    }
    while (__hip_atomic_load(&bar[144], __ATOMIC_RELAXED,
                             __HIP_MEMORY_SCOPE_AGENT) < g)
      __builtin_amdgcn_s_sleep(8);
    __builtin_amdgcn_fence(__ATOMIC_ACQUIRE, "agent");
  }
  __syncthreads();
}

// 256 blocks x 512 thr. Blocks [0,128): LSTM1 slice j (+ MLP); [128,256): LSTM2.
// Waves: w = bh*4 + kw; kw = k-split (4-way), bh = batch-half (2-way).
// Weights register-resident; split-k partials reduced via LDS tree (2 rounds).
__global__ __launch_bounds__(512, 2) void fused_lstm(
    const u16* __restrict__ W1i, const u16* __restrict__ W2i,
    const u16* __restrict__ W1m, const u16* __restrict__ W2m,
    const u16* __restrict__ Xb, u16* __restrict__ h1b, u16* __restrict__ h2b,
    u16* __restrict__ midb,
    const float* __restrict__ bs1, const float* __restrict__ bs2,
    const float* __restrict__ bm1, const float* __restrict__ bm2,
    float* __restrict__ out, unsigned* __restrict__ bar)
{
  extern __shared__ char smem[];
  const int tid = threadIdx.x, bid = blockIdx.x;
  const int w = tid >> 6, lane = tid & 63, q = lane >> 4, l16 = lane & 15;
  const int kw = w & 3, bh = w >> 2;
  const bool isL1 = bid < 128;
  const int j = isL1 ? bid : bid - 128;          // hc-slice: hc = j*8 .. j*8+8
  float* red = (float*)(smem + OFF_RED);
  u16* Wm = (u16*)(smem + OFF_WM);

  float cst[2][4] = {{0, 0, 0, 0}, {0, 0, 0, 0}};   // kw0: persistent cell state
  f32x4 bsv0 = {0, 0, 0, 0}, bsv1 = {0, 0, 0, 0};
  if (kw == 0) {
    const float* bs = isL1 ? bs1 : bs2;
    bsv0 = *(const f32x4*)(bs + (j * 8 + q) * 4);
    bsv1 = *(const f32x4*)(bs + (j * 8 + 4 + q) * 4);
  }

  if (isL1) {
    // ---- register-resident A: 2 m-tiles x 10 k-tiles (tiles kw*10..kw*10+9) ----
    bf16x8 A1[2][10];
#pragma unroll
    for (int mt = 0; mt < 2; ++mt)
#pragma unroll
      for (int s = 0; s < 10; ++s)
        A1[mt][s] = *(const bf16x8*)(W1i + (size_t)(j * 32 + mt * 16 + l16) * K1P +
                                     (size_t)(kw * 10 + s) * 32 + q * 8);
    // MLP weight slice -> LDS
    if (j < 64) {
      int m0 = (j & 7) * 16;
      for (int i = tid; i < 16 * 128; i += 512) {
        int r = i >> 7, c8 = i & 127;
        *(uint4*)(Wm + r * PKM1 + c8 * 8) =
            *(const uint4*)(W1m + ((size_t)(m0 + r)) * HH + c8 * 8);
      }
    } else {
      int v0 = ((j - 64) & 7) * 16;
      for (int i = tid; i < 16 * 16; i += 512) {
        int r = i >> 4, c8 = i & 15;
        *(uint4*)(Wm + r * PKM2 + c8 * 8) =
            *(const uint4*)(W2m + ((size_t)(v0 + r)) * MM + c8 * 8);
      }
    }
    f32x4 bmv = {0, 0, 0, 0};
    if (w == 3) {
      if (j < 64) bmv = *(const f32x4*)(bm1 + (j & 7) * 16 + q * 4);
      else        bmv = *(const f32x4*)(bm2 + ((j - 64) & 7) * 16 + q * 4);
    }
    __syncthreads();

    for (int p = 0; p < TT + 3; ++p) {
      const bool act = p < TT;
      if (act) {                        // ---- LSTM1, t = p ----
        const u16* h1p = h1b + (size_t)((p - 1) & 1) * H1N;
        f32x4 acc[2][4];
#pragma unroll
        for (int mt = 0; mt < 2; ++mt)
#pragma unroll
          for (int n = 0; n < 4; ++n) acc[mt][n] = (f32x4){0, 0, 0, 0};
        if (kw == 0) {                  // tiles 0..4 from x, 5..9 from h1prev
          const u16* bx = Xb + (size_t)p * 20480 +
                          ((size_t)q * 128 + bh * 64 + l16) * 8;
#pragma unroll
          for (int s = 0; s < 5; ++s)
            mac_step(A1[0][s], A1[1][s], bx + (size_t)s * 4096, acc);
          const u16* bp = h1p + ((size_t)q * 128 + bh * 64 + l16) * 8;
#pragma unroll
          for (int s = 0; s < 5; ++s)
            mac_step(A1[0][5 + s], A1[1][5 + s], bp + (size_t)s * 4096, acc);
        } else {                        // tiles kw*10.. from h1prev (lt0 = kw*10-5)
          const u16* bp = h1p + ((size_t)((kw * 10 - 5) * 4 + q) * 128 +
                                 bh * 64 + l16) * 8;
#pragma unroll
          for (int s = 0; s < 10; ++s)
            mac_step(A1[0][s], A1[1][s], bp + (size_t)s * 4096, acc);
        }
        // split-k tree reduction
        if (kw >= 2) red_write(red + (bh * 2 + kw - 2) * 2048, acc, lane);
        __syncthreads();
        if (kw < 2)  red_add(red + (bh * 2 + kw) * 2048, acc, lane);
        if (kw == 1) red_write(red + (bh * 2 + 1) * 2048, acc, lane);
        __syncthreads();
        if (kw == 0) {
          red_add(red + (bh * 2 + 1) * 2048, acc, lane);
          lstm_tail(acc, bsv0, bsv1, cst, smem, bh, lane, q, l16,
                    h1b + (size_t)(p & 1) * H1N + (size_t)j * HCH);
        }
      }
      if (w == 3) {                     // ---- MLP (wave 3 of L1 blocks) ----
        if (j < 64) {
          if (p >= 2 && p <= TT + 1) {  // mid, t = p-2
            int jm = j & 7, jb = j >> 3;
            const u16* bsrc = h2b + (size_t)(p & 1) * H1N + q * HCH +
                              (jb * 16 + l16) * 8;
            const u16* am = Wm + l16 * PKM1 + q * 8;
            f32x4 acc = {0, 0, 0, 0};
#pragma unroll 4
            for (int s = 0; s < 32; ++s) {
              bf16x8 bf = *(const bf16x8*)(bsrc + (size_t)s * 4096);
              bf16x8 af = *(const bf16x8*)(am + s * 32);
              acc = __builtin_amdgcn_mfma_f32_16x16x32_bf16(af, bf, acc, 0, 0, 0);
            }
            const float SC = 1.0507009873554804934193349852946f;
            const float AL = 1.6732632423543772848170429916717f;
            u16* st16 = (u16*)(smem + OFF_M);
#pragma unroll
            for (int r = 0; r < 4; ++r) {
              float v = acc[r] + bmv[r];
              v = v > 0.0f ? SC * v : SC * AL * (__expf(v) - 1.0f);
              st16[l16 * 16 + q * 4 + r] = f2bf(v);
            }
            if (lane < 16) {
              uint4 v0 = *(uint4*)(st16 + lane * 16);
              uint4 v1 = *(uint4*)(st16 + lane * 16 + 8);
              u16* mc = midb + (size_t)(p & 1) * MIDN;
              *(uint4*)(mc + (size_t)(2 * jm) * HCH + (jb * 16 + lane) * 8) = v0;
              *(uint4*)(mc + (size_t)(2 * jm + 1) * HCH + (jb * 16 + lane) * 8) = v1;
            }
          }
        } else if (p >= 3) {            // out, t = p-3
          int jj = j - 64, jv = jj & 7, jb = jj >> 3;
          const u16* bsrc = midb + (size_t)((p - 3) & 1) * MIDN + q * HCH +
                            (jb * 16 + l16) * 8;
          const u16* am = Wm + l16 * PKM2 + q * 8;
          f32x4 acc = {0, 0, 0, 0};
#pragma unroll
          for (int s = 0; s < 4; ++s) {
            bf16x8 bf = *(const bf16x8*)(bsrc + (size_t)s * 4096);
            bf16x8 af = *(const bf16x8*)(am + s * 32);
            acc = __builtin_amdgcn_mfma_f32_16x16x32_bf16(af, bf, acc, 0, 0, 0);
          }
          float* stf = (float*)(smem + OFF_M);
#pragma unroll
          for (int r = 0; r < 4; ++r) stf[l16 * 16 + q * 4 + r] = acc[r] + bmv[r];
          if (lane < 16) {
            float* orow = out + ((size_t)(p - 3) * BB + jb * 16 + lane) * VV + jv * 16;
            uint4* s4 = (uint4*)(stf + lane * 16);
            *(uint4*)(orow + 0)  = s4[0];
            *(uint4*)(orow + 4)  = s4[1];
            *(uint4*)(orow + 8)  = s4[2];
            *(uint4*)(orow + 12) = s4[3];
          }
        }
      }
      gbar(bar, (unsigned)p + 1u);
    }
  } else {
    // ---- LSTM2: register A: 2 m-tiles x 16 k-tiles (tiles kw*16..kw*16+15) ----
    bf16x8 A2[2][16];
#pragma unroll
    for (int mt = 0; mt < 2; ++mt)
#pragma unroll
      for (int s = 0; s < 16; ++s)
        A2[mt][s] = *(const bf16x8*)(W2i + (size_t)(j * 32 + mt * 16 + l16) * K2 +
                                     (size_t)(kw * 16 + s) * 32 + q * 8);

    for (int p = 0; p < TT + 3; ++p) {
      const bool act = (p >= 1 && p <= TT);
      if (act) {                        // ---- LSTM2, t = p-1 ----
        const int t = p - 1;
        const u16* h1c = h1b + (size_t)(t & 1) * H1N;
        const u16* h2p = h2b + (size_t)((t - 1) & 1) * H1N;
        const u16* src = (kw < 2) ? h1c : h2p;       // kw0,1: W_ih2·h1; kw2,3: W_hh2·h2
        const u16* bbase = src + ((size_t)((kw & 1) * 64 + q) * 128 +
                                  bh * 64 + l16) * 8;
        f32x4 acc[2][4];
#pragma unroll
        for (int mt = 0; mt < 2; ++mt)
#pragma unroll
          for (int n = 0; n < 4; ++n) acc[mt][n] = (f32x4){0, 0, 0, 0};
#pragma unroll
        for (int s = 0; s < 16; ++s)
          mac_step(A2[0][s], A2[1][s], bbase + (size_t)s * 4096, acc);

        if (kw >= 2) red_write(red + (bh * 2 + kw - 2) * 2048, acc, lane);
        __syncthreads();
        if (kw < 2)  red_add(red + (bh * 2 + kw) * 2048, acc, lane);
        if (kw == 1) red_write(red + (bh * 2 + 1) * 2048, acc, lane);
        __syncthreads();
        if (kw == 0) {
          red_add(red + (bh * 2 + 1) * 2048, acc, lane);
          lstm_tail(acc, bsv0, bsv1, cst, smem, bh, lane, q, l16,
                    h2b + (size_t)(t & 1) * H1N + (size_t)j * HCH);
        }
      }
      gbar(bar, (unsigned)p + 1u);
    }
  }
}

extern "C" void kernel_launch(void* const* d_in, const int* in_sizes, int n_in,
                              void* d_out, int out_size, void* d_ws, size_t ws_size,
                              hipStream_t stream)
{
  const float* x    = (const float*)d_in[0];
  const float* Wih1 = (const float*)d_in[1];
  const float* bih1 = (const float*)d_in[2];
  const float* Whh1 = (const float*)d_in[3];
  const float* bhh1 = (const float*)d_in[4];
  const float* Wih2 = (const float*)d_in[5];
  const float* bih2 = (const float*)d_in[6];
  const float* Whh2 = (const float*)d_in[7];
  const float* bhh2 = (const float*)d_in[8];
  const float* W1   = (const float*)d_in[9];
  const float* b1   = (const float*)d_in[10];
  const float* W2   = (const float*)d_in[11];
  const float* b2   = (const float*)d_in[12];
  float* out = (float*)d_out;
  (void)in_sizes; (void)n_in; (void)out_size;

  char* ws = (char*)d_ws;
  size_t off = 0;
  auto alloc = [&](size_t n) { char* p = ws + off; off += (n + 255) & ~(size_t)255; return p; };
  u16* W1i   = (u16*)alloc((size_t)4096 * K1P * 2);     // 10.49 MB
  u16* W2i   = (u16*)alloc((size_t)4096 * K2 * 2);      // 16.78 MB
  u16* W1m   = (u16*)alloc((size_t)MM * HH * 2);
  u16* W2m   = (u16*)alloc((size_t)VV * MM * 2);
  u16* Xb    = (u16*)alloc((size_t)TT * 20 * BB * 8 * 2);  // 41.94 MB
  float* bs1 = (float*)alloc(4096 * 4);
  float* bs2 = (float*)alloc(4096 * 4);
  // zeroed region (contiguous): h1b (+pad for zero-A overrun tiles), h2b, midb, bar
  u16* h1b   = (u16*)alloc(2 * (size_t)H1N * 2 + 32768);
  u16* h2b   = (u16*)alloc(2 * (size_t)H1N * 2);
  u16* midb  = (u16*)alloc(2 * (size_t)MIDN * 2);
  unsigned* bar = (unsigned*)alloc(4096);
  if (ws_size < off) return;  // ~71 MB required

  conv_w1i<<<4096, 256, 0, stream>>>(Wih1, Whh1, bih1, bhh1, W1i, bs1);
  conv_w2i<<<4096, 256, 0, stream>>>(Wih2, Whh2, bih2, bhh2, W2i, bs2);
  conv_mlpw<<<576, 256, 0, stream>>>(W1, W2, W1m, W2m);
  conv_x<<<TT * 20, 128, 0, stream>>>(x, Xb);
  {
    int n16 = (int)((2 * (size_t)H1N * 2 + 32768 + 2 * (size_t)H1N * 2 +
                     2 * (size_t)MIDN * 2 + 4096) / 16);
    zero_ws<<<(n16 + 255) / 256, 256, 0, stream>>>((uint4*)h1b, n16);
  }

  (void)hipFuncSetAttribute((const void*)fused_lstm,
                            hipFuncAttributeMaxDynamicSharedMemorySize, LDSZ);
  void* args[] = { (void*)&W1i, (void*)&W2i, (void*)&W1m, (void*)&W2m,
                   (void*)&Xb, (void*)&h1b, (void*)&h2b, (void*)&midb,
                   (void*)&bs1, (void*)&bs2, (void*)&b1, (void*)&b2,
                   (void*)&out, (void*)&bar };
  hipError_t err = hipLaunchCooperativeKernel((const void*)fused_lstm,
                                              dim3(256), dim3(512), args, LDSZ, stream);
  if (err != hipSuccess) {
    fused_lstm<<<dim3(256), dim3(512), LDSZ, stream>>>(W1i, W2i, W1m, W2m, Xb,
                                                       h1b, h2b, midb, bs1, bs2,
                                                       b1, b2, out, bar);
  }
}